// Round 4
// baseline (102.661 us; speedup 1.0000x reference)
//
#include <hip/hip_runtime.h>
#include <hip/hip_bf16.h>

// Weight-only int4 GEMM (M=2048, N=4096, K=4096, G=128):
//   1) dequant_w : packed int4 -> bf16 Wd[N][K] in d_ws
//   2) cvt_a     : fp32 A -> bf16 Ab[M][K] in d_ws
//   3) gemm32    : pipelined bf16 GEMM, BM=256 x BN=128, BK=64,
//        512 thr / 8 waves (4M x 2N, 64x64/wave), mfma_f32_32x32x16_bf16,
//        2 phases per K-tile (4 barriers), 3-deep LDS ring (144 KiB),
//        counted vmcnt(6), chunk-XOR swizzle (pre-swizzled global src +
//        swizzled ds_read), setprio around MFMA clusters.

using bf16x8 = __attribute__((ext_vector_type(8))) short;
using f32x16 = __attribute__((ext_vector_type(16))) float;

#define KK 4096
#define NN 4096
#define NT (KK / 64)

static __device__ __forceinline__ short f2bf(float f) {
    __hip_bfloat16 h = __float2bfloat16(f);
    return __builtin_bit_cast(short, h);
}

#define GLDS16(gptr, lptr) __builtin_amdgcn_global_load_lds( \
    (const __attribute__((address_space(1))) void*)(gptr),   \
    (__attribute__((address_space(3))) void*)(lptr), 16, 0, 0)

#define MFMA32 __builtin_amdgcn_mfma_f32_32x32x16_bf16

// ---------------- pre-pass 1: dequant W -> bf16 ----------------
__global__ __launch_bounds__(256) void dequant_w(
    const int* __restrict__ W, const float* __restrict__ SZ,
    short* __restrict__ Wd)
{
    const int idx = blockIdx.x * 256 + threadIdx.x;   // [0, NN*512)
    const int n   = idx >> 9;
    const int q4  = idx & 511;
    const int kh0 = q4 << 2;                          // int32 index in row
    const int g   = kh0 >> 6;                         // group (G=128)
    const float2 sz = *(const float2*)(SZ + ((size_t)g * NN + n) * 2);
    const float scale = sz.x;
    const float zs    = sz.y - 8.0f * sz.x;           // (q-8)*s+z = q*s+zs
    int4 p = *(const int4*)(W + (size_t)n * (KK / 2) + kh0);
    int vals[4] = {p.x, p.y, p.z, p.w};
    bf16x8 r;
    #pragma unroll
    for (int j = 0; j < 4; ++j) {
        int v = vals[j];
        r[2 * j]     = f2bf((float)((v >> 4) & 0xF) * scale + zs); // even k
        r[2 * j + 1] = f2bf((float)(v & 0xF) * scale + zs);        // odd k
    }
    *(bf16x8*)&Wd[(size_t)n * KK + (kh0 << 1)] = r;
}

// ---------------- pre-pass 2: A fp32 -> bf16 ----------------
__global__ __launch_bounds__(256) void cvt_a(
    const float* __restrict__ A, short* __restrict__ Ab)
{
    const int idx = blockIdx.x * 256 + threadIdx.x;
    const float4* s = (const float4*)(A + (size_t)idx * 8);
    float4 u = s[0], v = s[1];
    bf16x8 r;
    r[0] = f2bf(u.x); r[1] = f2bf(u.y); r[2] = f2bf(u.z); r[3] = f2bf(u.w);
    r[4] = f2bf(v.x); r[5] = f2bf(v.y); r[6] = f2bf(v.z); r[7] = f2bf(v.w);
    *(bf16x8*)&Ab[(size_t)idx * 8] = r;
}

// ---------------- main pipelined GEMM (32x32x16) ----------------
// LDS(row, chunk c) holds global(row, c ^ (row&7)); chunks are 16B.
__global__ __launch_bounds__(512, 2) void gemm32(
    const short* __restrict__ Ab, const short* __restrict__ Bb,
    float* __restrict__ C)
{
    __shared__ short sA[3 * 256 * 64];   // 96 KiB
    __shared__ short sB[3 * 128 * 64];   // 48 KiB

    const int tid  = threadIdx.x;
    const int lane = tid & 63;
    const int wave = tid >> 6;           // 0..7
    const int wm   = wave >> 1;          // m-offset wm*64 (0..3)
    const int wn   = wave & 1;           // n-offset wn*64
    const int bm   = blockIdx.y * 256;
    const int bn   = blockIdx.x * 128;

    // staging: per gload_lds instr the wave fills 8 rows x 8 chunks linearly;
    // global source pre-swizzled: row += lane>>3, chunk (lane&7)^(lane>>3)
    const int sl = lane >> 3;
    const int sc = (lane & 7) ^ sl;
    const short* aSt = Ab + (size_t)(bm + wave * 32 + sl) * KK + sc * 8;
    const short* bSt = Bb + (size_t)(bn + wave * 16 + sl) * KK + sc * 8;

    // 32x32x16 fragment reads: row = base + (lane&31);
    // logical chunk = slice*2 + (lane>>5); phys = logical ^ (lane&7)
    const int l31 = lane & 31;
    const int lx  = lane >> 5;
    const int l7  = lane & 7;
    const int px0 = ((0 + lx) ^ l7) * 8;   // slice 0
    const int px1 = ((2 + lx) ^ l7) * 8;   // slice 1
    const int px2 = ((4 + lx) ^ l7) * 8;   // slice 2
    const int px3 = ((6 + lx) ^ l7) * 8;   // slice 3
    const int aRd = (wm * 64 + l31) * 64;
    const int bRd = (wn * 64 + l31) * 64;

    f32x16 acc00 = {}, acc01 = {}, acc10 = {}, acc11 = {};

    // ---- prologue: stage K-tiles 0 and 1 (12 loads/thread in flight) ----
    #pragma unroll
    for (int l = 0; l < 4; ++l)
        GLDS16(aSt + (size_t)l * 8 * KK,      &sA[(wave * 32 + l * 8) * 64]);
    #pragma unroll
    for (int l = 0; l < 2; ++l)
        GLDS16(bSt + (size_t)l * 8 * KK,      &sB[(wave * 16 + l * 8) * 64]);
    #pragma unroll
    for (int l = 0; l < 4; ++l)
        GLDS16(aSt + (size_t)l * 8 * KK + 64, &sA[16384 + (wave * 32 + l * 8) * 64]);
    #pragma unroll
    for (int l = 0; l < 2; ++l)
        GLDS16(bSt + (size_t)l * 8 * KK + 64, &sB[8192 + (wave * 16 + l * 8) * 64]);
    asm volatile("s_waitcnt vmcnt(6)" ::: "memory");   // tile 0 landed
    __builtin_amdgcn_s_barrier();

    int cur = 0;
    for (int t = 0; t < NT; ++t) {
        const int nxt = (cur == 0) ? 2 : cur - 1;      // (t+2)%3
        const short* sAc = &sA[cur * 16384];
        const short* sBc = &sB[cur * 8192];
        short* sAn = &sA[nxt * 16384];
        short* sBn = &sB[nxt * 8192];
        const bool st = (t + 2 < NT);
        const int gk = (t + 2) * 64;

        // ---------- phase 0: k-slices 0,1 ----------
        {
            bf16x8 a00 = *(const bf16x8*)&sAc[aRd + px0];
            bf16x8 a01 = *(const bf16x8*)&sAc[aRd + px1];
            bf16x8 a10 = *(const bf16x8*)&sAc[aRd + 2048 + px0];
            bf16x8 a11 = *(const bf16x8*)&sAc[aRd + 2048 + px1];
            bf16x8 b00 = *(const bf16x8*)&sBc[bRd + px0];
            bf16x8 b01 = *(const bf16x8*)&sBc[bRd + px1];
            bf16x8 b10 = *(const bf16x8*)&sBc[bRd + 2048 + px0];
            bf16x8 b11 = *(const bf16x8*)&sBc[bRd + 2048 + px1];
            if (st) {
                GLDS16(aSt + (size_t)0 * 8 * KK + gk, sAn + (wave * 32 + 0) * 64);
                GLDS16(aSt + (size_t)1 * 8 * KK + gk, sAn + (wave * 32 + 8) * 64);
                GLDS16(bSt + (size_t)0 * 8 * KK + gk, sBn + (wave * 16 + 0) * 64);
            }
            __builtin_amdgcn_s_barrier();
            asm volatile("s_waitcnt lgkmcnt(0)" ::: "memory");
            __builtin_amdgcn_s_setprio(1);
            acc00 = MFMA32(a00, b00, acc00, 0, 0, 0);
            acc00 = MFMA32(a01, b01, acc00, 0, 0, 0);
            acc01 = MFMA32(a00, b10, acc01, 0, 0, 0);
            acc01 = MFMA32(a01, b11, acc01, 0, 0, 0);
            acc10 = MFMA32(a10, b00, acc10, 0, 0, 0);
            acc10 = MFMA32(a11, b01, acc10, 0, 0, 0);
            acc11 = MFMA32(a10, b10, acc11, 0, 0, 0);
            acc11 = MFMA32(a11, b11, acc11, 0, 0, 0);
            __builtin_amdgcn_s_setprio(0);
            __builtin_amdgcn_s_barrier();
        }

        // ---------- phase 1: k-slices 2,3 ----------
        {
            bf16x8 a00 = *(const bf16x8*)&sAc[aRd + px2];
            bf16x8 a01 = *(const bf16x8*)&sAc[aRd + px3];
            bf16x8 a10 = *(const bf16x8*)&sAc[aRd + 2048 + px2];
            bf16x8 a11 = *(const bf16x8*)&sAc[aRd + 2048 + px3];
            bf16x8 b00 = *(const bf16x8*)&sBc[bRd + px2];
            bf16x8 b01 = *(const bf16x8*)&sBc[bRd + px3];
            bf16x8 b10 = *(const bf16x8*)&sBc[bRd + 2048 + px2];
            bf16x8 b11 = *(const bf16x8*)&sBc[bRd + 2048 + px3];
            if (st) {
                GLDS16(aSt + (size_t)2 * 8 * KK + gk, sAn + (wave * 32 + 16) * 64);
                GLDS16(aSt + (size_t)3 * 8 * KK + gk, sAn + (wave * 32 + 24) * 64);
                GLDS16(bSt + (size_t)1 * 8 * KK + gk, sBn + (wave * 16 + 8) * 64);
            }
            __builtin_amdgcn_s_barrier();
            asm volatile("s_waitcnt lgkmcnt(0)" ::: "memory");
            __builtin_amdgcn_s_setprio(1);
            acc00 = MFMA32(a00, b00, acc00, 0, 0, 0);
            acc00 = MFMA32(a01, b01, acc00, 0, 0, 0);
            acc01 = MFMA32(a00, b10, acc01, 0, 0, 0);
            acc01 = MFMA32(a01, b11, acc01, 0, 0, 0);
            acc10 = MFMA32(a10, b00, acc10, 0, 0, 0);
            acc10 = MFMA32(a11, b01, acc10, 0, 0, 0);
            acc11 = MFMA32(a10, b10, acc11, 0, 0, 0);
            acc11 = MFMA32(a11, b11, acc11, 0, 0, 0);
            __builtin_amdgcn_s_setprio(0);
            // counted wait: tile t+1 must be fully landed before next iter
            if (t < NT - 2) {
                asm volatile("s_waitcnt vmcnt(6)" ::: "memory");
            } else {
                asm volatile("s_waitcnt vmcnt(0)" ::: "memory");
            }
            __builtin_amdgcn_s_barrier();
        }

        cur = (cur == 2) ? 0 : cur + 1;
    }

    // ---- epilogue: 32x32 C/D layout: col = lane&31,
    //      row = (reg&3) + 8*(reg>>2) + 4*(lane>>5) ----
    {
        const int crow = lx * 4;
        float* Cp = C + (size_t)(bm + wm * 64) * NN + bn + wn * 64;
        #pragma unroll
        for (int m = 0; m < 2; ++m) {
            #pragma unroll
            for (int qr = 0; qr < 4; ++qr) {
                #pragma unroll
                for (int j = 0; j < 4; ++j) {
                    const int row = m * 32 + crow + j + 8 * qr;
                    float* dst = Cp + (size_t)row * NN + l31;
                    if (m == 0) {
                        dst[0]  = acc00[qr * 4 + j];
                        dst[32] = acc01[qr * 4 + j];
                    } else {
                        dst[0]  = acc10[qr * 4 + j];
                        dst[32] = acc11[qr * 4 + j];
                    }
                }
            }
        }
    }
}

// ---------------- fallback: round-1 fused kernel ----------------
using f32x4 = __attribute__((ext_vector_type(4))) float;
#define LDKF 72
__global__ __launch_bounds__(256) void wq4_gemm_fused(
    const float* __restrict__ A, const int* __restrict__ W,
    const float* __restrict__ SZ, float* __restrict__ C, int M)
{
    __shared__ short sA[128 * LDKF];
    __shared__ short sB[128 * LDKF];
    const int tid = threadIdx.x, lane = tid & 63, wave = tid >> 6;
    const int wr = (wave >> 1) << 6, wc = (wave & 1) << 6;
    const int bm = blockIdx.y * 128, bn = blockIdx.x * 128;
    const int ar = tid >> 2, ac = (tid & 3) << 4;
    const int br = tid >> 1, bh = (tid & 1) << 4;
    const float* Arow0 = A + (size_t)(bm + ar) * KK + ac;
    const float* Arow1 = A + (size_t)(bm + 64 + ar) * KK + ac;
    const int*   Wrow  = W + (size_t)(bn + br) * (KK / 2) + bh;
    const float* SZrow = SZ + (size_t)(bn + br) * 2;
    f32x4 acc[4][4] = {};
    for (int k0 = 0; k0 < KK; k0 += 64) {
        {
            const float4* s0 = (const float4*)(Arow0 + k0);
            const float4* s1 = (const float4*)(Arow1 + k0);
            float4 a0 = s0[0], a1 = s0[1], a2 = s0[2], a3 = s0[3];
            float4 b0 = s1[0], b1 = s1[1], b2 = s1[2], b3 = s1[3];
            auto cvt8 = [](float4 u, float4 v) -> bf16x8 {
                bf16x8 r;
                r[0] = f2bf(u.x); r[1] = f2bf(u.y); r[2] = f2bf(u.z); r[3] = f2bf(u.w);
                r[4] = f2bf(v.x); r[5] = f2bf(v.y); r[6] = f2bf(v.z); r[7] = f2bf(v.w);
                return r;
            };
            *(bf16x8*)&sA[ar * LDKF + ac]            = cvt8(a0, a1);
            *(bf16x8*)&sA[ar * LDKF + ac + 8]        = cvt8(a2, a3);
            *(bf16x8*)&sA[(64 + ar) * LDKF + ac]     = cvt8(b0, b1);
            *(bf16x8*)&sA[(64 + ar) * LDKF + ac + 8] = cvt8(b2, b3);
        }
        {
            const int g = k0 >> 7;
            const float2 sz = *(const float2*)(SZrow + (size_t)g * NN * 2);
            const float scale = sz.x, zs = sz.y - 8.0f * sz.x;
            const int4* src = (const int4*)(Wrow + (k0 >> 1));
            #pragma unroll
            for (int i = 0; i < 4; ++i) {
                int4 p = src[i];
                int vals[4] = {p.x, p.y, p.z, p.w};
                bf16x8 r;
                #pragma unroll
                for (int j = 0; j < 4; ++j) {
                    int v = vals[j];
                    r[2 * j]     = f2bf((float)((v >> 4) & 0xF) * scale + zs);
                    r[2 * j + 1] = f2bf((float)(v & 0xF) * scale + zs);
                }
                *(bf16x8*)&sB[br * LDKF + (bh << 1) + (i << 3)] = r;
            }
        }
        __syncthreads();
        #pragma unroll
        for (int ks = 0; ks < 2; ++ks) {
            const int col = (ks << 5) + ((lane >> 4) << 3);
            bf16x8 af[4], bfr[4];
            #pragma unroll
            for (int m = 0; m < 4; ++m)
                af[m] = *(const bf16x8*)&sA[(wr + m * 16 + (lane & 15)) * LDKF + col];
            #pragma unroll
            for (int n = 0; n < 4; ++n)
                bfr[n] = *(const bf16x8*)&sB[(wc + n * 16 + (lane & 15)) * LDKF + col];
            #pragma unroll
            for (int m = 0; m < 4; ++m)
                #pragma unroll
                for (int n = 0; n < 4; ++n)
                    acc[m][n] = __builtin_amdgcn_mfma_f32_16x16x32_bf16(
                        af[m], bfr[n], acc[m][n], 0, 0, 0);
        }
        __syncthreads();
    }
    float* Cp = C + (size_t)(bm + wr) * NN + bn + wc;
    const int cr = (lane >> 4) << 2, cc = lane & 15;
    #pragma unroll
    for (int m = 0; m < 4; ++m)
        #pragma unroll
        for (int j = 0; j < 4; ++j) {
            float* dst = Cp + (size_t)(m * 16 + cr + j) * NN + cc;
            #pragma unroll
            for (int n = 0; n < 4; ++n) dst[n * 16] = acc[m][n][j];
        }
}

extern "C" void kernel_launch(void* const* d_in, const int* in_sizes, int n_in,
                              void* d_out, int out_size, void* d_ws, size_t ws_size,
                              hipStream_t stream) {
    const float* A  = (const float*)d_in[0];
    const int*   W  = (const int*)d_in[1];
    const float* SZ = (const float*)d_in[2];
    float* C = (float*)d_out;

    const int M = in_sizes[0] / KK;   // 2048

    const size_t wd_elems = (size_t)NN * KK;
    const size_t ab_elems = (size_t)M * KK;
    const size_t need = (wd_elems + ab_elems) * sizeof(short);

    if (ws_size >= need && (M % 256) == 0) {
        short* Wd = (short*)d_ws;
        short* Ab = Wd + wd_elems;
        dequant_w<<<NN * (KK / 8) / 256, 256, 0, stream>>>(W, SZ, Wd);
        cvt_a<<<(int)(ab_elems / 8 / 256), 256, 0, stream>>>(A, Ab);
        dim3 grid(NN / 128, M / 256);
        gemm32<<<grid, dim3(512), 0, stream>>>(Ab, Wd, C);
    } else {
        dim3 grid(NN / 128, M / 128);
        wq4_gemm_fused<<<grid, dim3(256), 0, stream>>>(A, W, SZ, C, M);
    }
}

// Round 5
// 93.777 us; speedup vs baseline: 1.0947x; 1.0947x over previous
//
#include <hip/hip_runtime.h>
#include <hip/hip_bf16.h>

// Weight-only int4 GEMM (M=2048, N=4096, K=4096, G=128):
//   1) dequant_w : packed int4 -> bf16 Wd[N][K] in d_ws
//   2) cvt_a     : fp32 A -> bf16 Ab[M][K] in d_ws
//   3) gemm_pl   : pipelined bf16 GEMM, BM=256 x BN=128, BK=64,
//        512 thr / 8 waves (4M x 2N, 64x64/wave), mfma_f32_32x32x16_bf16.
//        ONE barrier per K-tile: 3-deep LDS ring; register ping/pong of
//        fragment sets so every ds_read's latency hides under the other
//        phase's 8-MFMA cluster; counted vmcnt(3); chunk-XOR swizzle.

using bf16x8 = __attribute__((ext_vector_type(8))) short;
using f32x16 = __attribute__((ext_vector_type(16))) float;

#define KK 4096
#define NN 4096
#define NT (KK / 64)

static __device__ __forceinline__ short f2bf(float f) {
    __hip_bfloat16 h = __float2bfloat16(f);
    return __builtin_bit_cast(short, h);
}

#define GLDS16(gptr, lptr) __builtin_amdgcn_global_load_lds( \
    (const __attribute__((address_space(1))) void*)(gptr),   \
    (__attribute__((address_space(3))) void*)(lptr), 16, 0, 0)

#define MFMA32 __builtin_amdgcn_mfma_f32_32x32x16_bf16

// ---------------- pre-pass 1: dequant W -> bf16 ----------------
__global__ __launch_bounds__(256) void dequant_w(
    const int* __restrict__ W, const float* __restrict__ SZ,
    short* __restrict__ Wd)
{
    const int idx = blockIdx.x * 256 + threadIdx.x;   // [0, NN*512)
    const int n   = idx >> 9;
    const int q4  = idx & 511;
    const int kh0 = q4 << 2;                          // int32 index in row
    const int g   = kh0 >> 6;                         // group (G=128)
    const float2 sz = *(const float2*)(SZ + ((size_t)g * NN + n) * 2);
    const float scale = sz.x;
    const float zs    = sz.y - 8.0f * sz.x;           // (q-8)*s+z = q*s+zs
    int4 p = *(const int4*)(W + (size_t)n * (KK / 2) + kh0);
    int vals[4] = {p.x, p.y, p.z, p.w};
    bf16x8 r;
    #pragma unroll
    for (int j = 0; j < 4; ++j) {
        int v = vals[j];
        r[2 * j]     = f2bf((float)((v >> 4) & 0xF) * scale + zs); // even k
        r[2 * j + 1] = f2bf((float)(v & 0xF) * scale + zs);        // odd k
    }
    *(bf16x8*)&Wd[(size_t)n * KK + (kh0 << 1)] = r;
}

// ---------------- pre-pass 2: A fp32 -> bf16 ----------------
__global__ __launch_bounds__(256) void cvt_a(
    const float* __restrict__ A, short* __restrict__ Ab)
{
    const int idx = blockIdx.x * 256 + threadIdx.x;
    const float4* s = (const float4*)(A + (size_t)idx * 8);
    float4 u = s[0], v = s[1];
    bf16x8 r;
    r[0] = f2bf(u.x); r[1] = f2bf(u.y); r[2] = f2bf(u.z); r[3] = f2bf(u.w);
    r[4] = f2bf(v.x); r[5] = f2bf(v.y); r[6] = f2bf(v.z); r[7] = f2bf(v.w);
    *(bf16x8*)&Ab[(size_t)idx * 8] = r;
}

// ---------------- main pipelined GEMM (1 barrier / K-tile) ----------------
// LDS(row, chunk c) holds global(row, c ^ (row&7)); chunks are 16B.
__global__ __launch_bounds__(512, 2) void gemm_pl(
    const short* __restrict__ Ab, const short* __restrict__ Bb,
    float* __restrict__ C)
{
    __shared__ short sA[3 * 256 * 64];   // 96 KiB
    __shared__ short sB[3 * 128 * 64];   // 48 KiB

    const int tid  = threadIdx.x;
    const int lane = tid & 63;
    const int wave = tid >> 6;           // 0..7
    const int wm   = wave >> 1;          // m-offset wm*64 (0..3)
    const int wn   = wave & 1;           // n-offset wn*64
    const int bm   = blockIdx.y * 256;
    const int bn   = blockIdx.x * 128;

    // staging: per gload_lds instr the wave fills 8 rows x 8 chunks linearly;
    // global source pre-swizzled: row += lane>>3, chunk (lane&7)^(lane>>3)
    const int sl = lane >> 3;
    const int sc = (lane & 7) ^ sl;
    const short* aSt = Ab + (size_t)(bm + wave * 32 + sl) * KK + sc * 8;
    const short* bSt = Bb + (size_t)(bn + wave * 16 + sl) * KK + sc * 8;

    // 32x32x16 fragment reads: row = base + (lane&31);
    // logical chunk = slice*2 + (lane>>5); phys = logical ^ (lane&7)
    const int l31 = lane & 31;
    const int lx  = lane >> 5;
    const int l7  = lane & 7;
    const int px0 = ((0 + lx) ^ l7) * 8;   // k-slice 0
    const int px1 = ((2 + lx) ^ l7) * 8;   // k-slice 1
    const int px2 = ((4 + lx) ^ l7) * 8;   // k-slice 2
    const int px3 = ((6 + lx) ^ l7) * 8;   // k-slice 3
    const int aRd = (wm * 64 + l31) * 64;
    const int bRd = (wn * 64 + l31) * 64;

    f32x16 acc00 = {}, acc01 = {}, acc10 = {}, acc11 = {};
    bf16x8 pA00, pA01, pA10, pA11, pB00, pB01, pB10, pB11;  // phase-0 frags
    bf16x8 qA00, qA01, qA10, qA11, qB00, qB01, qB10, qB11;  // phase-1 frags

    // ---- prologue: stage K-tiles 0 and 1 ----
    #pragma unroll
    for (int l = 0; l < 4; ++l)
        GLDS16(aSt + (size_t)l * 8 * KK,      &sA[(wave * 32 + l * 8) * 64]);
    #pragma unroll
    for (int l = 0; l < 2; ++l)
        GLDS16(bSt + (size_t)l * 8 * KK,      &sB[(wave * 16 + l * 8) * 64]);
    #pragma unroll
    for (int l = 0; l < 4; ++l)
        GLDS16(aSt + (size_t)l * 8 * KK + 64, &sA[16384 + (wave * 32 + l * 8) * 64]);
    #pragma unroll
    for (int l = 0; l < 2; ++l)
        GLDS16(bSt + (size_t)l * 8 * KK + 64, &sB[8192 + (wave * 16 + l * 8) * 64]);
    asm volatile("s_waitcnt vmcnt(6)" ::: "memory");   // tile 0 landed
    __builtin_amdgcn_s_barrier();

    // load phase-0 frags of tile 0
    pA00 = *(const bf16x8*)&sA[aRd + px0];
    pA01 = *(const bf16x8*)&sA[aRd + px1];
    pA10 = *(const bf16x8*)&sA[aRd + 2048 + px0];
    pA11 = *(const bf16x8*)&sA[aRd + 2048 + px1];
    pB00 = *(const bf16x8*)&sB[bRd + px0];
    pB01 = *(const bf16x8*)&sB[bRd + px1];
    pB10 = *(const bf16x8*)&sB[bRd + 2048 + px0];
    pB11 = *(const bf16x8*)&sB[bRd + 2048 + px1];
    asm volatile("s_waitcnt lgkmcnt(0)" ::: "memory");
    __builtin_amdgcn_sched_barrier(0);

    int cur = 0;
    for (int t = 0; t < NT; ++t) {
        const int nxt1 = (cur == 2) ? 0 : cur + 1;     // (t+1)%3
        const int nxt2 = (nxt1 == 2) ? 0 : nxt1 + 1;   // (t+2)%3
        const short* sAc = &sA[cur * 16384];
        const short* sBc = &sB[cur * 8192];
        const short* sA1 = &sA[nxt1 * 16384];
        const short* sB1 = &sB[nxt1 * 8192];
        short* sAn = &sA[nxt2 * 16384];
        short* sBn = &sB[nxt2 * 8192];
        const bool st = (t + 2 < NT);
        const int gk = (t + 2) * 64;

        // -- issue phase-1 frag reads (k-slices 2,3) + first half staging --
        qA00 = *(const bf16x8*)&sAc[aRd + px2];
        qA01 = *(const bf16x8*)&sAc[aRd + px3];
        qA10 = *(const bf16x8*)&sAc[aRd + 2048 + px2];
        qA11 = *(const bf16x8*)&sAc[aRd + 2048 + px3];
        qB00 = *(const bf16x8*)&sBc[bRd + px2];
        qB01 = *(const bf16x8*)&sBc[bRd + px3];
        qB10 = *(const bf16x8*)&sBc[bRd + 2048 + px2];
        qB11 = *(const bf16x8*)&sBc[bRd + 2048 + px3];
        if (st) {
            GLDS16(aSt + (size_t)0 * 8 * KK + gk, sAn + (wave * 32 + 0) * 64);
            GLDS16(aSt + (size_t)1 * 8 * KK + gk, sAn + (wave * 32 + 8) * 64);
            GLDS16(bSt + (size_t)0 * 8 * KK + gk, sBn + (wave * 16 + 0) * 64);
        }
        __builtin_amdgcn_sched_barrier(0);

        // -- MFMA on phase-0 frags (overlaps the reads above) --
        __builtin_amdgcn_s_setprio(1);
        acc00 = MFMA32(pA00, pB00, acc00, 0, 0, 0);
        acc00 = MFMA32(pA01, pB01, acc00, 0, 0, 0);
        acc01 = MFMA32(pA00, pB10, acc01, 0, 0, 0);
        acc01 = MFMA32(pA01, pB11, acc01, 0, 0, 0);
        acc10 = MFMA32(pA10, pB00, acc10, 0, 0, 0);
        acc10 = MFMA32(pA11, pB01, acc10, 0, 0, 0);
        acc11 = MFMA32(pA10, pB10, acc11, 0, 0, 0);
        acc11 = MFMA32(pA11, pB11, acc11, 0, 0, 0);
        __builtin_amdgcn_s_setprio(0);

        // -- phase-1 frags landed; tile t+1 staged; single barrier --
        asm volatile("s_waitcnt lgkmcnt(0)" ::: "memory");
        __builtin_amdgcn_sched_barrier(0);
        if (t < NT - 2) {
            asm volatile("s_waitcnt vmcnt(3)" ::: "memory");
        } else {
            asm volatile("s_waitcnt vmcnt(0)" ::: "memory");
        }
        __builtin_amdgcn_s_barrier();

        // -- issue next-tile phase-0 frag reads + second half staging --
        if (t + 1 < NT) {
            pA00 = *(const bf16x8*)&sA1[aRd + px0];
            pA01 = *(const bf16x8*)&sA1[aRd + px1];
            pA10 = *(const bf16x8*)&sA1[aRd + 2048 + px0];
            pA11 = *(const bf16x8*)&sA1[aRd + 2048 + px1];
            pB00 = *(const bf16x8*)&sB1[bRd + px0];
            pB01 = *(const bf16x8*)&sB1[bRd + px1];
            pB10 = *(const bf16x8*)&sB1[bRd + 2048 + px0];
            pB11 = *(const bf16x8*)&sB1[bRd + 2048 + px1];
        }
        if (st) {
            GLDS16(aSt + (size_t)2 * 8 * KK + gk, sAn + (wave * 32 + 16) * 64);
            GLDS16(aSt + (size_t)3 * 8 * KK + gk, sAn + (wave * 32 + 24) * 64);
            GLDS16(bSt + (size_t)1 * 8 * KK + gk, sBn + (wave * 16 + 8) * 64);
        }
        __builtin_amdgcn_sched_barrier(0);

        // -- MFMA on phase-1 frags (overlaps the reads above) --
        __builtin_amdgcn_s_setprio(1);
        acc00 = MFMA32(qA00, qB00, acc00, 0, 0, 0);
        acc00 = MFMA32(qA01, qB01, acc00, 0, 0, 0);
        acc01 = MFMA32(qA00, qB10, acc01, 0, 0, 0);
        acc01 = MFMA32(qA01, qB11, acc01, 0, 0, 0);
        acc10 = MFMA32(qA10, qB00, acc10, 0, 0, 0);
        acc10 = MFMA32(qA11, qB01, acc10, 0, 0, 0);
        acc11 = MFMA32(qA10, qB10, acc11, 0, 0, 0);
        acc11 = MFMA32(qA11, qB11, acc11, 0, 0, 0);
        __builtin_amdgcn_s_setprio(0);

        asm volatile("s_waitcnt lgkmcnt(0)" ::: "memory");
        __builtin_amdgcn_sched_barrier(0);

        cur = nxt1;
    }

    // ---- epilogue: 32x32 C/D layout: col = lane&31,
    //      row = (reg&3) + 8*(reg>>2) + 4*(lane>>5) ----
    {
        const int crow = lx * 4;
        float* Cp = C + (size_t)(bm + wm * 64) * NN + bn + wn * 64;
        #pragma unroll
        for (int m = 0; m < 2; ++m) {
            #pragma unroll
            for (int qr = 0; qr < 4; ++qr) {
                #pragma unroll
                for (int j = 0; j < 4; ++j) {
                    const int row = m * 32 + crow + j + 8 * qr;
                    float* dst = Cp + (size_t)row * NN + l31;
                    if (m == 0) {
                        dst[0]  = acc00[qr * 4 + j];
                        dst[32] = acc01[qr * 4 + j];
                    } else {
                        dst[0]  = acc10[qr * 4 + j];
                        dst[32] = acc11[qr * 4 + j];
                    }
                }
            }
        }
    }
}

// ---------------- fallback: round-1 fused kernel ----------------
using f32x4 = __attribute__((ext_vector_type(4))) float;
#define LDKF 72
__global__ __launch_bounds__(256) void wq4_gemm_fused(
    const float* __restrict__ A, const int* __restrict__ W,
    const float* __restrict__ SZ, float* __restrict__ C, int M)
{
    __shared__ short sA[128 * LDKF];
    __shared__ short sB[128 * LDKF];
    const int tid = threadIdx.x, lane = tid & 63, wave = tid >> 6;
    const int wr = (wave >> 1) << 6, wc = (wave & 1) << 6;
    const int bm = blockIdx.y * 128, bn = blockIdx.x * 128;
    const int ar = tid >> 2, ac = (tid & 3) << 4;
    const int br = tid >> 1, bh = (tid & 1) << 4;
    const float* Arow0 = A + (size_t)(bm + ar) * KK + ac;
    const float* Arow1 = A + (size_t)(bm + 64 + ar) * KK + ac;
    const int*   Wrow  = W + (size_t)(bn + br) * (KK / 2) + bh;
    const float* SZrow = SZ + (size_t)(bn + br) * 2;
    f32x4 acc[4][4] = {};
    for (int k0 = 0; k0 < KK; k0 += 64) {
        {
            const float4* s0 = (const float4*)(Arow0 + k0);
            const float4* s1 = (const float4*)(Arow1 + k0);
            float4 a0 = s0[0], a1 = s0[1], a2 = s0[2], a3 = s0[3];
            float4 b0 = s1[0], b1 = s1[1], b2 = s1[2], b3 = s1[3];
            auto cvt8 = [](float4 u, float4 v) -> bf16x8 {
                bf16x8 r;
                r[0] = f2bf(u.x); r[1] = f2bf(u.y); r[2] = f2bf(u.z); r[3] = f2bf(u.w);
                r[4] = f2bf(v.x); r[5] = f2bf(v.y); r[6] = f2bf(v.z); r[7] = f2bf(v.w);
                return r;
            };
            *(bf16x8*)&sA[ar * LDKF + ac]            = cvt8(a0, a1);
            *(bf16x8*)&sA[ar * LDKF + ac + 8]        = cvt8(a2, a3);
            *(bf16x8*)&sA[(64 + ar) * LDKF + ac]     = cvt8(b0, b1);
            *(bf16x8*)&sA[(64 + ar) * LDKF + ac + 8] = cvt8(b2, b3);
        }
        {
            const int g = k0 >> 7;
            const float2 sz = *(const float2*)(SZrow + (size_t)g * NN * 2);
            const float scale = sz.x, zs = sz.y - 8.0f * sz.x;
            const int4* src = (const int4*)(Wrow + (k0 >> 1));
            #pragma unroll
            for (int i = 0; i < 4; ++i) {
                int4 p = src[i];
                int vals[4] = {p.x, p.y, p.z, p.w};
                bf16x8 r;
                #pragma unroll
                for (int j = 0; j < 4; ++j) {
                    int v = vals[j];
                    r[2 * j]     = f2bf((float)((v >> 4) & 0xF) * scale + zs);
                    r[2 * j + 1] = f2bf((float)(v & 0xF) * scale + zs);
                }
                *(bf16x8*)&sB[br * LDKF + (bh << 1) + (i << 3)] = r;
            }
        }
        __syncthreads();
        #pragma unroll
        for (int ks = 0; ks < 2; ++ks) {
            const int col = (ks << 5) + ((lane >> 4) << 3);
            bf16x8 af[4], bfr[4];
            #pragma unroll
            for (int m = 0; m < 4; ++m)
                af[m] = *(const bf16x8*)&sA[(wr + m * 16 + (lane & 15)) * LDKF + col];
            #pragma unroll
            for (int n = 0; n < 4; ++n)
                bfr[n] = *(const bf16x8*)&sB[(wc + n * 16 + (lane & 15)) * LDKF + col];
            #pragma unroll
            for (int m = 0; m < 4; ++m)
                #pragma unroll
                for (int n = 0; n < 4; ++n)
                    acc[m][n] = __builtin_amdgcn_mfma_f32_16x16x32_bf16(
                        af[m], bfr[n], acc[m][n], 0, 0, 0);
        }
        __syncthreads();
    }
    float* Cp = C + (size_t)(bm + wr) * NN + bn + wc;
    const int cr = (lane >> 4) << 2, cc = lane & 15;
    #pragma unroll
    for (int m = 0; m < 4; ++m)
        #pragma unroll
        for (int j = 0; j < 4; ++j) {
            float* dst = Cp + (size_t)(m * 16 + cr + j) * NN + cc;
            #pragma unroll
            for (int n = 0; n < 4; ++n) dst[n * 16] = acc[m][n][j];
        }
}

extern "C" void kernel_launch(void* const* d_in, const int* in_sizes, int n_in,
                              void* d_out, int out_size, void* d_ws, size_t ws_size,
                              hipStream_t stream) {
    const float* A  = (const float*)d_in[0];
    const int*   W  = (const int*)d_in[1];
    const float* SZ = (const float*)d_in[2];
    float* C = (float*)d_out;

    const int M = in_sizes[0] / KK;   // 2048

    const size_t wd_elems = (size_t)NN * KK;
    const size_t ab_elems = (size_t)M * KK;
    const size_t need = (wd_elems + ab_elems) * sizeof(short);

    if (ws_size >= need && (M % 256) == 0) {
        short* Wd = (short*)d_ws;
        short* Ab = Wd + wd_elems;
        dequant_w<<<NN * (KK / 8) / 256, 256, 0, stream>>>(W, SZ, Wd);
        cvt_a<<<(int)(ab_elems / 8 / 256), 256, 0, stream>>>(A, Ab);
        dim3 grid(NN / 128, M / 256);
        gemm_pl<<<grid, dim3(512), 0, stream>>>(Ab, Wd, C);
    } else {
        dim3 grid(NN / 128, M / 128);
        wq4_gemm_fused<<<grid, dim3(256), 0, stream>>>(A, W, SZ, C, M);
    }
}